// Round 1
// baseline (1807.958 us; speedup 1.0000x reference)
//
#include <hip/hip_runtime.h>
#include <hip/hip_bf16.h>
#include <math.h>

#define Bsz 2
#define Tt  2048
#define Cc  1024
#define Hh  16
#define Dd  64

// ---------------- fp32 tiled GEMM: Y[4096x1024] = X[4096x1024] @ W[1024x1024] + bias ----------------
// mode 0: Y row-major [4096,1024]
// mode 1: Y written as [B,H,T,D]  (split-heads permute fused into epilogue)
#define BM 128
#define BN 128
#define BK 16

__global__ __launch_bounds__(256) void gemm128(const float* __restrict__ X,
                                               const float* __restrict__ W,
                                               const float* __restrict__ bias,
                                               float* __restrict__ Y, int mode) {
  __shared__ float As[BK][BM];
  __shared__ float Bs2[BK][BN];
  const int bn = blockIdx.x, bm = blockIdx.y;
  const int row0 = bm * BM, col0 = bn * BN;
  const int tid = threadIdx.x;
  const int tm = tid >> 4, tn = tid & 15;

  float acc[8][8];
#pragma unroll
  for (int i = 0; i < 8; ++i)
#pragma unroll
    for (int j = 0; j < 8; ++j) acc[i][j] = 0.f;

  for (int k0 = 0; k0 < Cc; k0 += BK) {
#pragma unroll
    for (int i = 0; i < 2; ++i) {
      int idx = tid + i * 256;          // 0..511 float4 slots
      int r = idx >> 2, kq = (idx & 3) << 2;
      const float4 a = *(const float4*)(X + (size_t)(row0 + r) * Cc + k0 + kq);
      As[kq + 0][r] = a.x;
      As[kq + 1][r] = a.y;
      As[kq + 2][r] = a.z;
      As[kq + 3][r] = a.w;
    }
#pragma unroll
    for (int i = 0; i < 2; ++i) {
      int idx = tid + i * 256;
      int r = idx >> 5, c = (idx & 31) << 2;
      *(float4*)&Bs2[r][c] = *(const float4*)(W + (size_t)(k0 + r) * Cc + col0 + c);
    }
    __syncthreads();
#pragma unroll
    for (int kk = 0; kk < BK; ++kk) {
      float a[8], b[8];
      *(float4*)&a[0] = *(const float4*)&As[kk][tm * 8];
      *(float4*)&a[4] = *(const float4*)&As[kk][tm * 8 + 4];
      *(float4*)&b[0] = *(const float4*)&Bs2[kk][tn * 8];
      *(float4*)&b[4] = *(const float4*)&Bs2[kk][tn * 8 + 4];
#pragma unroll
      for (int i = 0; i < 8; ++i)
#pragma unroll
        for (int j = 0; j < 8; ++j) acc[i][j] = fmaf(a[i], b[j], acc[i][j]);
    }
    __syncthreads();
  }

  float bias8[8];
  *(float4*)&bias8[0] = *(const float4*)(bias + col0 + tn * 8);
  *(float4*)&bias8[4] = *(const float4*)(bias + col0 + tn * 8 + 4);

#pragma unroll
  for (int i = 0; i < 8; ++i) {
    int r = row0 + tm * 8 + i;
#pragma unroll
    for (int jc = 0; jc < 8; jc += 4) {
      float4 o;
      o.x = acc[i][jc + 0] + bias8[jc + 0];
      o.y = acc[i][jc + 1] + bias8[jc + 1];
      o.z = acc[i][jc + 2] + bias8[jc + 2];
      o.w = acc[i][jc + 3] + bias8[jc + 3];
      int c = col0 + tn * 8 + jc;
      if (mode == 0) {
        *(float4*)(Y + (size_t)r * Cc + c) = o;
      } else {
        int b = r >> 11, t = r & (Tt - 1);
        int h = c >> 6, d = c & 63;
        *(float4*)(Y + ((((size_t)b * Hh + h) * Tt + t) * Dd + d)) = o;
      }
    }
  }
}

// ---------------- RoPE in-place on q and k, layout [B,H,T,D] ----------------
__global__ void rope_qk(float* __restrict__ q, float* __restrict__ k) {
  int idx = blockIdx.x * blockDim.x + threadIdx.x;  // [0, B*H*T*32)
  int p = idx & 31;
  int t = (idx >> 5) & (Tt - 1);
  int bh = idx >> 16;  // T*32 = 65536 = 2^16
  float inv = powf(10000.f, -(float)(2 * p) / 64.f);
  float ang = (float)t * inv;
  float s, c;
  sincosf(ang, &s, &c);
  size_t base = ((size_t)bh * Tt + t) * Dd;
  float q1 = q[base + p], q2 = q[base + p + 32];
  q[base + p]      = q1 * c - q2 * s;
  q[base + p + 32] = q2 * c + q1 * s;
  float k1 = k[base + p], k2 = k[base + p + 32];
  k[base + p]      = k1 * c - k2 * s;
  k[base + p + 32] = k2 * c + k1 * s;
}

// ---------------- sliding-window attention ----------------
// one thread per query row; K/V tiles (32x64 fp32) staged in LDS; online softmax.
// out written as [B,T,C] (heads merged) so final GEMM reads it row-major.
__global__ __launch_bounds__(256) void attn_kernel(const float* __restrict__ q,
                                                   const float* __restrict__ k,
                                                   const float* __restrict__ v,
                                                   float* __restrict__ out) {
  const int bh = blockIdx.y;                       // b*16 + h
  const int tq = blockIdx.x * 256 + threadIdx.x;   // query index

  const float* qp = q + ((size_t)bh * Tt + tq) * Dd;
  float qr[64];
#pragma unroll
  for (int i = 0; i < 16; ++i) *(float4*)&qr[i * 4] = *(const float4*)(qp + i * 4);

  float m = -1e30f, l = 0.f;
  float acc[64];
#pragma unroll
  for (int d = 0; d < 64; ++d) acc[d] = 0.f;

  const int jstart = (tq - 511) > 0 ? (tq - 511) : 0;
  const int j0 = ((int)blockIdx.x * 256 - 511) > 0 ? ((int)blockIdx.x * 256 - 511) : 0;
  const int jt0 = j0 & ~31;   // tile-align

  __shared__ float Ks[32][64];
  __shared__ float Vs[32][64];

  for (int jt = jt0; jt < Tt; jt += 32) {
    __syncthreads();  // protect previous tile's LDS from overwrite
    const float* kbase = k + ((size_t)bh * Tt + jt) * Dd;
    const float* vbase = v + ((size_t)bh * Tt + jt) * Dd;
#pragma unroll
    for (int i = 0; i < 2; ++i) {
      int idx = threadIdx.x + i * 256;   // 0..511 float4 slots (32*16)
      int r = idx >> 4, c = (idx & 15) << 2;
      *(float4*)&Ks[r][c] = *(const float4*)(kbase + r * 64 + c);
      *(float4*)&Vs[r][c] = *(const float4*)(vbase + r * 64 + c);
    }
    __syncthreads();

    for (int jj = 0; jj < 32; ++jj) {
      int j = jt + jj;
      if (j < jstart) continue;  // sliding-window mask (no causal cap)
      float s = 0.f;
#pragma unroll
      for (int d4 = 0; d4 < 16; ++d4) {
        float4 kk4 = *(const float4*)&Ks[jj][d4 * 4];
        s = fmaf(qr[d4 * 4 + 0], kk4.x, s);
        s = fmaf(qr[d4 * 4 + 1], kk4.y, s);
        s = fmaf(qr[d4 * 4 + 2], kk4.z, s);
        s = fmaf(qr[d4 * 4 + 3], kk4.w, s);
      }
      s *= 0.125f;  // 1/sqrt(64)
      if (s > m) {
        float sc = __expf(m - s);
        m = s;
        l *= sc;
#pragma unroll
        for (int d = 0; d < 64; ++d) acc[d] *= sc;
      }
      float p = __expf(s - m);
      l += p;
#pragma unroll
      for (int d4 = 0; d4 < 16; ++d4) {
        float4 vv = *(const float4*)&Vs[jj][d4 * 4];
        acc[d4 * 4 + 0] = fmaf(p, vv.x, acc[d4 * 4 + 0]);
        acc[d4 * 4 + 1] = fmaf(p, vv.y, acc[d4 * 4 + 1]);
        acc[d4 * 4 + 2] = fmaf(p, vv.z, acc[d4 * 4 + 2]);
        acc[d4 * 4 + 3] = fmaf(p, vv.w, acc[d4 * 4 + 3]);
      }
    }
  }

  const float inv_l = 1.f / l;
  const int b = bh >> 4, h = bh & 15;
  float* op = out + ((size_t)b * Tt + tq) * Cc + h * 64;
#pragma unroll
  for (int d4 = 0; d4 < 16; ++d4) {
    float4 o;
    o.x = acc[d4 * 4 + 0] * inv_l;
    o.y = acc[d4 * 4 + 1] * inv_l;
    o.z = acc[d4 * 4 + 2] * inv_l;
    o.w = acc[d4 * 4 + 3] * inv_l;
    *(float4*)(op + d4 * 4) = o;
  }
}

extern "C" void kernel_launch(void* const* d_in, const int* in_sizes, int n_in,
                              void* d_out, int out_size, void* d_ws, size_t ws_size,
                              hipStream_t stream) {
  const float* x  = (const float*)d_in[0];
  const float* Wq = (const float*)d_in[1];
  const float* bq = (const float*)d_in[2];
  const float* Wk = (const float*)d_in[3];
  const float* bk = (const float*)d_in[4];
  const float* Wv = (const float*)d_in[5];
  const float* bv = (const float*)d_in[6];
  const float* Wo = (const float*)d_in[7];
  const float* bo = (const float*)d_in[8];

  float* ws = (float*)d_ws;
  float* q     = ws;                 // [B,H,T,D] 4M floats
  float* kbuf  = ws + 4194304;       // [B,H,T,D]
  float* vbuf  = ws + 8388608;       // [B,H,T,D]
  float* attnb = ws + 12582912;      // [B,T,C]

  dim3 gg(Cc / BN, (Bsz * Tt) / BM);  // (8, 32)
  gemm128<<<gg, 256, 0, stream>>>(x, Wq, bq, q, 1);
  gemm128<<<gg, 256, 0, stream>>>(x, Wk, bk, kbuf, 1);
  gemm128<<<gg, 256, 0, stream>>>(x, Wv, bv, vbuf, 1);

  rope_qk<<<(Bsz * Hh * Tt * 32) / 256, 256, 0, stream>>>(q, kbuf);

  dim3 ga(Tt / 256, Bsz * Hh);        // (8, 32)
  attn_kernel<<<ga, 256, 0, stream>>>(q, kbuf, vbuf, attnb);

  gemm128<<<gg, 256, 0, stream>>>(attnb, Wo, bo, (float*)d_out, 0);
}

// Round 2
// 1378.638 us; speedup vs baseline: 1.3114x; 1.3114x over previous
//
#include <hip/hip_runtime.h>
#include <hip/hip_bf16.h>
#include <math.h>

#define Bsz 2
#define Tt  2048
#define Cc  1024
#define Hh  16
#define Dd  64

// ---------------- fp32 tiled GEMM: Y[4096x1024] = X[4096x1024] @ W[1024x1024] + bias ----------------
// mode 0: Y row-major [4096,1024]
// mode 1: Y written as [B,H,T,D]  (split-heads permute fused into epilogue)
#define BM 128
#define BN 128
#define BK 16

__global__ __launch_bounds__(256) void gemm128(const float* __restrict__ X,
                                               const float* __restrict__ W,
                                               const float* __restrict__ bias,
                                               float* __restrict__ Y, int mode) {
  __shared__ float As[BK][BM];
  __shared__ float Bs2[BK][BN];
  const int bn = blockIdx.x, bm = blockIdx.y;
  const int row0 = bm * BM, col0 = bn * BN;
  const int tid = threadIdx.x;
  const int tm = tid >> 4, tn = tid & 15;

  float acc[8][8];
#pragma unroll
  for (int i = 0; i < 8; ++i)
#pragma unroll
    for (int j = 0; j < 8; ++j) acc[i][j] = 0.f;

  for (int k0 = 0; k0 < Cc; k0 += BK) {
#pragma unroll
    for (int i = 0; i < 2; ++i) {
      int idx = tid + i * 256;          // 0..511 float4 slots
      int r = idx >> 2, kq = (idx & 3) << 2;
      const float4 a = *(const float4*)(X + (size_t)(row0 + r) * Cc + k0 + kq);
      As[kq + 0][r] = a.x;
      As[kq + 1][r] = a.y;
      As[kq + 2][r] = a.z;
      As[kq + 3][r] = a.w;
    }
#pragma unroll
    for (int i = 0; i < 2; ++i) {
      int idx = tid + i * 256;
      int r = idx >> 5, c = (idx & 31) << 2;
      *(float4*)&Bs2[r][c] = *(const float4*)(W + (size_t)(k0 + r) * Cc + col0 + c);
    }
    __syncthreads();
#pragma unroll
    for (int kk = 0; kk < BK; ++kk) {
      float a[8], b[8];
      *(float4*)&a[0] = *(const float4*)&As[kk][tm * 8];
      *(float4*)&a[4] = *(const float4*)&As[kk][tm * 8 + 4];
      *(float4*)&b[0] = *(const float4*)&Bs2[kk][tn * 8];
      *(float4*)&b[4] = *(const float4*)&Bs2[kk][tn * 8 + 4];
#pragma unroll
      for (int i = 0; i < 8; ++i)
#pragma unroll
        for (int j = 0; j < 8; ++j) acc[i][j] = fmaf(a[i], b[j], acc[i][j]);
    }
    __syncthreads();
  }

  float bias8[8];
  *(float4*)&bias8[0] = *(const float4*)(bias + col0 + tn * 8);
  *(float4*)&bias8[4] = *(const float4*)(bias + col0 + tn * 8 + 4);

#pragma unroll
  for (int i = 0; i < 8; ++i) {
    int r = row0 + tm * 8 + i;
#pragma unroll
    for (int jc = 0; jc < 8; jc += 4) {
      float4 o;
      o.x = acc[i][jc + 0] + bias8[jc + 0];
      o.y = acc[i][jc + 1] + bias8[jc + 1];
      o.z = acc[i][jc + 2] + bias8[jc + 2];
      o.w = acc[i][jc + 3] + bias8[jc + 3];
      int c = col0 + tn * 8 + jc;
      if (mode == 0) {
        *(float4*)(Y + (size_t)r * Cc + c) = o;
      } else {
        int b = r >> 11, t = r & (Tt - 1);
        int h = c >> 6, d = c & 63;
        *(float4*)(Y + ((((size_t)b * Hh + h) * Tt + t) * Dd + d)) = o;
      }
    }
  }
}

// ---------------- RoPE in-place on q and k, layout [B,H,T,D] ----------------
__global__ void rope_qk(float* __restrict__ q, float* __restrict__ k) {
  int idx = blockIdx.x * blockDim.x + threadIdx.x;  // [0, B*H*T*32)
  int p = idx & 31;
  int t = (idx >> 5) & (Tt - 1);
  int bh = idx >> 16;  // T*32 = 65536 = 2^16
  // 10000^(-2p/64) = exp2(-p * log2(10000)/32), log2(10000)=13.287712
  float inv = exp2f(-(float)p * (13.2877123795494f / 32.f));
  float ang = (float)t * inv;
  float s, c;
  sincosf(ang, &s, &c);
  size_t base = ((size_t)bh * Tt + t) * Dd;
  float q1 = q[base + p], q2 = q[base + p + 32];
  q[base + p]      = q1 * c - q2 * s;
  q[base + p + 32] = q2 * c + q1 * s;
  float k1 = k[base + p], k2 = k[base + p + 32];
  k[base + p]      = k1 * c - k2 * s;
  k[base + p + 32] = k2 * c + k1 * s;
}

// ---------------- sliding-window attention, 4-way d-split ----------------
// 4 threads per query: thread (q, ds) owns d in [ds*16, ds*16+16).
// QK dot: 16-dim partial + 2x shfl_xor within quad; m/l replicated across quad.
// 64 queries per block (256 threads), grid (32, B*H) = 1024 blocks.
__global__ __launch_bounds__(256) void attn_kernel(const float* __restrict__ q,
                                                   const float* __restrict__ k,
                                                   const float* __restrict__ v,
                                                   float* __restrict__ out) {
  const int bh = blockIdx.y;                 // b*16 + h
  const int qlocal = threadIdx.x >> 2;       // 0..63
  const int ds = threadIdx.x & 3;            // 0..3
  const int d0 = ds * 16;
  const int tq = blockIdx.x * 64 + qlocal;   // query index

  const float* qp = q + ((size_t)bh * Tt + tq) * Dd + d0;
  float qr[16];
#pragma unroll
  for (int i = 0; i < 4; ++i) *(float4*)&qr[i * 4] = *(const float4*)(qp + i * 4);

  float m = -1e30f, l = 0.f;
  float acc[16];
#pragma unroll
  for (int d = 0; d < 16; ++d) acc[d] = 0.f;

  const int jstart = (tq - 511) > 0 ? (tq - 511) : 0;
  const int q0 = blockIdx.x * 64;
  const int j0 = (q0 - 511) > 0 ? (q0 - 511) : 0;
  const int jt0 = j0 & ~31;   // tile-aligned earliest key any query in block needs

  __shared__ float Ks[32][64];
  __shared__ float Vs[32][64];

  for (int jt = jt0; jt < Tt; jt += 32) {
    __syncthreads();  // protect previous tile's LDS from overwrite
    const float* kbase = k + ((size_t)bh * Tt + jt) * Dd;
    const float* vbase = v + ((size_t)bh * Tt + jt) * Dd;
#pragma unroll
    for (int i = 0; i < 2; ++i) {
      int idx = threadIdx.x + i * 256;   // 0..511 float4 slots (32 rows x 16 slots)
      int r = idx >> 4, c = (idx & 15) << 2;
      *(float4*)&Ks[r][c] = *(const float4*)(kbase + r * 64 + c);
      *(float4*)&Vs[r][c] = *(const float4*)(vbase + r * 64 + c);
    }
    __syncthreads();

#pragma unroll 2
    for (int jj = 0; jj < 32; ++jj) {
      int j = jt + jj;
      if (j < jstart) continue;  // sliding-window mask (no causal cap)
      float s = 0.f;
#pragma unroll
      for (int c4 = 0; c4 < 4; ++c4) {
        float4 kk4 = *(const float4*)&Ks[jj][d0 + c4 * 4];
        s = fmaf(qr[c4 * 4 + 0], kk4.x, s);
        s = fmaf(qr[c4 * 4 + 1], kk4.y, s);
        s = fmaf(qr[c4 * 4 + 2], kk4.z, s);
        s = fmaf(qr[c4 * 4 + 3], kk4.w, s);
      }
      s += __shfl_xor(s, 1);
      s += __shfl_xor(s, 2);
      s *= 0.125f;  // 1/sqrt(64)
      if (s > m) {
        float sc = __expf(m - s);
        m = s;
        l *= sc;
#pragma unroll
        for (int d = 0; d < 16; ++d) acc[d] *= sc;
      }
      float p = __expf(s - m);
      l += p;
#pragma unroll
      for (int c4 = 0; c4 < 4; ++c4) {
        float4 vv = *(const float4*)&Vs[jj][d0 + c4 * 4];
        acc[c4 * 4 + 0] = fmaf(p, vv.x, acc[c4 * 4 + 0]);
        acc[c4 * 4 + 1] = fmaf(p, vv.y, acc[c4 * 4 + 1]);
        acc[c4 * 4 + 2] = fmaf(p, vv.z, acc[c4 * 4 + 2]);
        acc[c4 * 4 + 3] = fmaf(p, vv.w, acc[c4 * 4 + 3]);
      }
    }
  }

  const float inv_l = 1.f / l;
  const int b = bh >> 4, h = bh & 15;
  float* op = out + ((size_t)b * Tt + tq) * Cc + h * 64 + d0;
#pragma unroll
  for (int c4 = 0; c4 < 4; ++c4) {
    float4 o;
    o.x = acc[c4 * 4 + 0] * inv_l;
    o.y = acc[c4 * 4 + 1] * inv_l;
    o.z = acc[c4 * 4 + 2] * inv_l;
    o.w = acc[c4 * 4 + 3] * inv_l;
    *(float4*)(op + c4 * 4) = o;
  }
}

extern "C" void kernel_launch(void* const* d_in, const int* in_sizes, int n_in,
                              void* d_out, int out_size, void* d_ws, size_t ws_size,
                              hipStream_t stream) {
  const float* x  = (const float*)d_in[0];
  const float* Wq = (const float*)d_in[1];
  const float* bq = (const float*)d_in[2];
  const float* Wk = (const float*)d_in[3];
  const float* bk = (const float*)d_in[4];
  const float* Wv = (const float*)d_in[5];
  const float* bv = (const float*)d_in[6];
  const float* Wo = (const float*)d_in[7];
  const float* bo = (const float*)d_in[8];

  float* ws = (float*)d_ws;
  float* q     = ws;                 // [B,H,T,D] 4M floats
  float* kbuf  = ws + 4194304;       // [B,H,T,D]
  float* vbuf  = ws + 8388608;       // [B,H,T,D]
  float* attnb = ws + 12582912;      // [B,T,C]

  dim3 gg(Cc / BN, (Bsz * Tt) / BM);  // (8, 32)
  gemm128<<<gg, 256, 0, stream>>>(x, Wq, bq, q, 1);
  gemm128<<<gg, 256, 0, stream>>>(x, Wk, bk, kbuf, 1);
  gemm128<<<gg, 256, 0, stream>>>(x, Wv, bv, vbuf, 1);

  rope_qk<<<(Bsz * Hh * Tt * 32) / 256, 256, 0, stream>>>(q, kbuf);

  dim3 ga(Tt / 64, Bsz * Hh);         // (32, 32) = 1024 blocks
  attn_kernel<<<ga, 256, 0, stream>>>(q, kbuf, vbuf, attnb);

  gemm128<<<gg, 256, 0, stream>>>(attnb, Wo, bo, (float*)d_out, 0);
}

// Round 3
// 739.379 us; speedup vs baseline: 2.4452x; 1.8646x over previous
//
#include <hip/hip_runtime.h>
#include <hip/hip_bf16.h>
#include <math.h>

#define Bsz 2
#define Tt  2048
#define Cc  1024
#define Hh  16
#define Dd  64

typedef __attribute__((ext_vector_type(8))) short short8v;
typedef __attribute__((ext_vector_type(4))) float f32x4;

static __device__ __forceinline__ short f2bf(float f) {
  __hip_bfloat16 h = __float2bfloat16(f);
  return __builtin_bit_cast(short, h);
}

// ---------------- fp32 tiled GEMM (unchanged from round 2) ----------------
#define BM 128
#define BN 128
#define BK 16

__global__ __launch_bounds__(256) void gemm128(const float* __restrict__ X,
                                               const float* __restrict__ W,
                                               const float* __restrict__ bias,
                                               float* __restrict__ Y, int mode) {
  __shared__ float As[BK][BM];
  __shared__ float Bs2[BK][BN];
  const int bn = blockIdx.x, bm = blockIdx.y;
  const int row0 = bm * BM, col0 = bn * BN;
  const int tid = threadIdx.x;
  const int tm = tid >> 4, tn = tid & 15;

  float acc[8][8];
#pragma unroll
  for (int i = 0; i < 8; ++i)
#pragma unroll
    for (int j = 0; j < 8; ++j) acc[i][j] = 0.f;

  for (int k0 = 0; k0 < Cc; k0 += BK) {
#pragma unroll
    for (int i = 0; i < 2; ++i) {
      int idx = tid + i * 256;
      int r = idx >> 2, kq = (idx & 3) << 2;
      const float4 a = *(const float4*)(X + (size_t)(row0 + r) * Cc + k0 + kq);
      As[kq + 0][r] = a.x;
      As[kq + 1][r] = a.y;
      As[kq + 2][r] = a.z;
      As[kq + 3][r] = a.w;
    }
#pragma unroll
    for (int i = 0; i < 2; ++i) {
      int idx = tid + i * 256;
      int r = idx >> 5, c = (idx & 31) << 2;
      *(float4*)&Bs2[r][c] = *(const float4*)(W + (size_t)(k0 + r) * Cc + col0 + c);
    }
    __syncthreads();
#pragma unroll
    for (int kk = 0; kk < BK; ++kk) {
      float a[8], b[8];
      *(float4*)&a[0] = *(const float4*)&As[kk][tm * 8];
      *(float4*)&a[4] = *(const float4*)&As[kk][tm * 8 + 4];
      *(float4*)&b[0] = *(const float4*)&Bs2[kk][tn * 8];
      *(float4*)&b[4] = *(const float4*)&Bs2[kk][tn * 8 + 4];
#pragma unroll
      for (int i = 0; i < 8; ++i)
#pragma unroll
        for (int j = 0; j < 8; ++j) acc[i][j] = fmaf(a[i], b[j], acc[i][j]);
    }
    __syncthreads();
  }

  float bias8[8];
  *(float4*)&bias8[0] = *(const float4*)(bias + col0 + tn * 8);
  *(float4*)&bias8[4] = *(const float4*)(bias + col0 + tn * 8 + 4);

#pragma unroll
  for (int i = 0; i < 8; ++i) {
    int r = row0 + tm * 8 + i;
#pragma unroll
    for (int jc = 0; jc < 8; jc += 4) {
      float4 o;
      o.x = acc[i][jc + 0] + bias8[jc + 0];
      o.y = acc[i][jc + 1] + bias8[jc + 1];
      o.z = acc[i][jc + 2] + bias8[jc + 2];
      o.w = acc[i][jc + 3] + bias8[jc + 3];
      int c = col0 + tn * 8 + jc;
      if (mode == 0) {
        *(float4*)(Y + (size_t)r * Cc + c) = o;
      } else {
        int b = r >> 11, t = r & (Tt - 1);
        int h = c >> 6, d = c & 63;
        *(float4*)(Y + ((((size_t)b * Hh + h) * Tt + t) * Dd + d)) = o;
      }
    }
  }
}

// ---------------- RoPE in-place (unchanged) ----------------
__global__ void rope_qk(float* __restrict__ q, float* __restrict__ k) {
  int idx = blockIdx.x * blockDim.x + threadIdx.x;
  int p = idx & 31;
  int t = (idx >> 5) & (Tt - 1);
  int bh = idx >> 16;
  float inv = exp2f(-(float)p * (13.2877123795494f / 32.f));
  float ang = (float)t * inv;
  float s, c;
  sincosf(ang, &s, &c);
  size_t base = ((size_t)bh * Tt + t) * Dd;
  float q1 = q[base + p], q2 = q[base + p + 32];
  q[base + p]      = q1 * c - q2 * s;
  q[base + p + 32] = q2 * c + q1 * s;
  float k1 = k[base + p], k2 = k[base + p + 32];
  k[base + p]      = k1 * c - k2 * s;
  k[base + p + 32] = k2 * c + k1 * s;
}

// ---------------- MFMA flash attention, sliding window ----------------
// 4 waves/block, 16 queries/wave (QBLK=64). Swapped QK^T: S^T = mfma(K, Q)
// -> each lane owns ONE query (q = lane&15), keys 4g+r / 16+4g+r in regs.
// PV: O^T = mfma(V^T, P) with V's LDS columns psi-permuted so P's register
// order IS the B-fragment order (psi(8g+e) = e<4 ? 4g+e : 16+4g+e-4).
__global__ __launch_bounds__(256) void attn_mfma(const float* __restrict__ q,
                                                 const float* __restrict__ k,
                                                 const float* __restrict__ v,
                                                 float* __restrict__ out) {
  // XCD-grouped swizzle: 8 XCDs x 4 bh x 32 qblocks (bijective, 1024 blocks)
  const int n = blockIdx.x;
  const int xcd = n & 7;
  const int slot = n >> 3;
  const int bh = xcd * 4 + (slot >> 5);
  const int qblk = slot & 31;
  const int q0 = qblk * 64;

  const int lane = threadIdx.x & 63;
  const int wv = threadIdx.x >> 6;     // wave 0..3
  const int l15 = lane & 15;
  const int g = lane >> 4;             // 0..3
  const int qbase = q0 + wv * 16;
  const int qrow = qbase + l15;

  const float* qg = q + (size_t)bh * Tt * Dd;
  const float* kg = k + (size_t)bh * Tt * Dd;
  const float* vg = v + (size_t)bh * Tt * Dd;

  // Q fragments (scale 1/8 folded in): dims 8g..8g+7 and 32+8g..+7
  short8v qlo, qhi;
  {
    const float* qp = qg + (size_t)qrow * Dd;
    float4 f0 = *(const float4*)(qp + 8 * g);
    float4 f1 = *(const float4*)(qp + 8 * g + 4);
    float4 f2 = *(const float4*)(qp + 32 + 8 * g);
    float4 f3 = *(const float4*)(qp + 32 + 8 * g + 4);
    qlo[0] = f2bf(f0.x * 0.125f); qlo[1] = f2bf(f0.y * 0.125f);
    qlo[2] = f2bf(f0.z * 0.125f); qlo[3] = f2bf(f0.w * 0.125f);
    qlo[4] = f2bf(f1.x * 0.125f); qlo[5] = f2bf(f1.y * 0.125f);
    qlo[6] = f2bf(f1.z * 0.125f); qlo[7] = f2bf(f1.w * 0.125f);
    qhi[0] = f2bf(f2.x * 0.125f); qhi[1] = f2bf(f2.y * 0.125f);
    qhi[2] = f2bf(f2.z * 0.125f); qhi[3] = f2bf(f2.w * 0.125f);
    qhi[4] = f2bf(f3.x * 0.125f); qhi[5] = f2bf(f3.y * 0.125f);
    qhi[6] = f2bf(f3.z * 0.125f); qhi[7] = f2bf(f3.w * 0.125f);
  }

  __shared__ short Klds[32 * 72];   // [32 keys][64 dims + pad8], rows 144B
  __shared__ short Vt[64 * 40];     // [64 dims][32 keys psi-perm + pad8], rows 80B

  f32x4 oacc[4];
#pragma unroll
  for (int i = 0; i < 4; ++i) oacc[i] = (f32x4){0.f, 0.f, 0.f, 0.f};
  float mrun = -1e30f, lrun = 0.f;

  const int cs0 = (q0 - 511) > 0 ? (q0 - 511) : 0;
  const int cstart = cs0 & ~31;

  for (int jt = cstart; jt < Tt; jt += 32) {
    __syncthreads();
    // ---- stage K -> Klds bf16 (natural key order) ----
    {
      int kr = threadIdx.x >> 3;          // 0..31
      int kc = (threadIdx.x & 7) * 8;     // 0..56
      const float* src = kg + (size_t)(jt + kr) * Dd + kc;
      float4 f0 = *(const float4*)src;
      float4 f1 = *(const float4*)(src + 4);
      short8v kvv;
      kvv[0] = f2bf(f0.x); kvv[1] = f2bf(f0.y); kvv[2] = f2bf(f0.z); kvv[3] = f2bf(f0.w);
      kvv[4] = f2bf(f1.x); kvv[5] = f2bf(f1.y); kvv[6] = f2bf(f1.z); kvv[7] = f2bf(f1.w);
      *(short8v*)&Klds[kr * 72 + kc] = kvv;
    }
    // ---- stage V -> Vt (transposed, psi-permuted columns) ----
    {
      int vr = (threadIdx.x >> 4) * 2;    // even key 0..30
      int vc = (threadIdx.x & 15) * 4;    // dim 0..60
      const float* s0 = vg + (size_t)(jt + vr) * Dd + vc;
      float4 a = *(const float4*)s0;
      float4 b = *(const float4*)(s0 + Dd);
      int cc = (vr < 16) ? ((vr >> 2) * 8 + (vr & 3))
                         : (((vr - 16) >> 2) * 8 + 4 + (vr & 3));
      unsigned w0 = (unsigned)(unsigned short)f2bf(a.x) | ((unsigned)(unsigned short)f2bf(b.x) << 16);
      unsigned w1 = (unsigned)(unsigned short)f2bf(a.y) | ((unsigned)(unsigned short)f2bf(b.y) << 16);
      unsigned w2 = (unsigned)(unsigned short)f2bf(a.z) | ((unsigned)(unsigned short)f2bf(b.z) << 16);
      unsigned w3 = (unsigned)(unsigned short)f2bf(a.w) | ((unsigned)(unsigned short)f2bf(b.w) << 16);
      *(unsigned*)&Vt[(vc + 0) * 40 + cc] = w0;
      *(unsigned*)&Vt[(vc + 1) * 40 + cc] = w1;
      *(unsigned*)&Vt[(vc + 2) * 40 + cc] = w2;
      *(unsigned*)&Vt[(vc + 3) * 40 + cc] = w3;
    }
    __syncthreads();

    if (jt + 32 <= qbase - 511) continue;  // chunk fully below this wave's window

    // ---- QK^T (swapped): S^T[key][q] ----
    short8v k00 = *(short8v*)&Klds[l15 * 72 + 8 * g];
    short8v k01 = *(short8v*)&Klds[l15 * 72 + 32 + 8 * g];
    short8v k10 = *(short8v*)&Klds[(16 + l15) * 72 + 8 * g];
    short8v k11 = *(short8v*)&Klds[(16 + l15) * 72 + 32 + 8 * g];
    f32x4 zf = (f32x4){0.f, 0.f, 0.f, 0.f};
    f32x4 s0 = __builtin_amdgcn_mfma_f32_16x16x32_bf16(k00, qlo, zf, 0, 0, 0);
    s0 = __builtin_amdgcn_mfma_f32_16x16x32_bf16(k01, qhi, s0, 0, 0, 0);
    f32x4 s1 = __builtin_amdgcn_mfma_f32_16x16x32_bf16(k10, qlo, zf, 0, 0, 0);
    s1 = __builtin_amdgcn_mfma_f32_16x16x32_bf16(k11, qhi, s1, 0, 0, 0);

    float se[8];
#pragma unroll
    for (int r = 0; r < 4; ++r) { se[r] = s0[r]; se[4 + r] = s1[r]; }

    if (jt < qbase - 496) {  // boundary chunk: apply window mask
      int th = qrow - 511 - jt;   // local key < th is masked
#pragma unroll
      for (int r = 0; r < 4; ++r) {
        if (4 * g + r < th) se[r] = -1e30f;
        if (16 + 4 * g + r < th) se[4 + r] = -1e30f;
      }
    }

    float cmax = se[0];
#pragma unroll
    for (int i = 1; i < 8; ++i) cmax = fmaxf(cmax, se[i]);
    cmax = fmaxf(cmax, __shfl_xor(cmax, 16));
    cmax = fmaxf(cmax, __shfl_xor(cmax, 32));

    float mnew = fmaxf(fmaxf(mrun, cmax), -1e29f);
    float fac = __expf(mrun - mnew);
    float p[8], psum = 0.f;
#pragma unroll
    for (int i = 0; i < 8; ++i) { p[i] = __expf(se[i] - mnew); psum += p[i]; }
    psum += __shfl_xor(psum, 16);
    psum += __shfl_xor(psum, 32);
    lrun = lrun * fac + psum;
    mrun = mnew;
#pragma unroll
    for (int t2 = 0; t2 < 4; ++t2)
#pragma unroll
      for (int r = 0; r < 4; ++r) oacc[t2][r] *= fac;

    short8v pf;
#pragma unroll
    for (int i = 0; i < 8; ++i) pf[i] = f2bf(p[i]);

    // ---- PV: O^T += mfma(V^T, P) per 16-dim tile ----
#pragma unroll
    for (int t2 = 0; t2 < 4; ++t2) {
      short8v vf = *(short8v*)&Vt[(16 * t2 + l15) * 40 + 8 * g];
      oacc[t2] = __builtin_amdgcn_mfma_f32_16x16x32_bf16(vf, pf, oacc[t2], 0, 0, 0);
    }
  }

  // ---- epilogue: scale by 1/l, write out[B,T,C] ----
  const float invl = 1.f / lrun;
  const int b = bh >> 4, h = bh & 15;
  float* op = out + ((size_t)b * Tt + qrow) * Cc + h * Dd;
#pragma unroll
  for (int t2 = 0; t2 < 4; ++t2)
#pragma unroll
    for (int r = 0; r < 4; ++r)
      op[16 * t2 + 4 * g + r] = oacc[t2][r] * invl;
}

extern "C" void kernel_launch(void* const* d_in, const int* in_sizes, int n_in,
                              void* d_out, int out_size, void* d_ws, size_t ws_size,
                              hipStream_t stream) {
  const float* x  = (const float*)d_in[0];
  const float* Wq = (const float*)d_in[1];
  const float* bq = (const float*)d_in[2];
  const float* Wk = (const float*)d_in[3];
  const float* bk = (const float*)d_in[4];
  const float* Wv = (const float*)d_in[5];
  const float* bv = (const float*)d_in[6];
  const float* Wo = (const float*)d_in[7];
  const float* bo = (const float*)d_in[8];

  float* ws = (float*)d_ws;
  float* q     = ws;                 // [B,H,T,D]
  float* kbuf  = ws + 4194304;
  float* vbuf  = ws + 8388608;
  float* attnb = ws + 12582912;      // [B,T,C]

  dim3 gg(Cc / BN, (Bsz * Tt) / BM);
  gemm128<<<gg, 256, 0, stream>>>(x, Wq, bq, q, 1);
  gemm128<<<gg, 256, 0, stream>>>(x, Wk, bk, kbuf, 1);
  gemm128<<<gg, 256, 0, stream>>>(x, Wv, bv, vbuf, 1);

  rope_qk<<<(Bsz * Hh * Tt * 32) / 256, 256, 0, stream>>>(q, kbuf);

  attn_mfma<<<1024, 256, 0, stream>>>(q, kbuf, vbuf, attnb);

  gemm128<<<gg, 256, 0, stream>>>(attnb, Wo, bo, (float*)d_out, 0);
}

// Round 4
// 233.192 us; speedup vs baseline: 7.7531x; 3.1707x over previous
//
#include <hip/hip_runtime.h>
#include <hip/hip_bf16.h>
#include <math.h>

#define Bsz 2
#define Tt  2048
#define Cc  1024
#define Hh  16
#define Dd  64

typedef __attribute__((ext_vector_type(8))) short short8v;
typedef __attribute__((ext_vector_type(4))) short short4v;
typedef __attribute__((ext_vector_type(4))) float f32x4;

static __device__ __forceinline__ short f2bf(float f) {
  __hip_bfloat16 h = __float2bfloat16(f);
  return __builtin_bit_cast(short, h);
}
static __device__ __forceinline__ float bf2f(short s) {
  unsigned u = ((unsigned)(unsigned short)s) << 16;
  return __builtin_bit_cast(float, u);
}
static __device__ __forceinline__ void gll16(const void* g, void* l) {
  __builtin_amdgcn_global_load_lds((const __attribute__((address_space(1))) unsigned int*)g,
                                   (__attribute__((address_space(3))) unsigned int*)l, 16, 0, 0);
}

// ---------------- prepass: split x into bf16 hi/lo ----------------
__global__ void split_x(const float* __restrict__ x, short* __restrict__ xhi,
                        short* __restrict__ xlo) {
  int t = blockIdx.x * 256 + threadIdx.x;   // 8 elems each, 4096*1024 total
  const float* s = x + (size_t)t * 8;
  float4 a = *(const float4*)s, b = *(const float4*)(s + 4);
  float vv[8] = {a.x, a.y, a.z, a.w, b.x, b.y, b.z, b.w};
  short8v h, l;
#pragma unroll
  for (int e = 0; e < 8; ++e) {
    short hb = f2bf(vv[e]);
    h[e] = hb;
    l[e] = f2bf(vv[e] - bf2f(hb));
  }
  *(short8v*)(xhi + (size_t)t * 8) = h;
  *(short8v*)(xlo + (size_t)t * 8) = l;
}

// ---------------- prepass: split + transpose W -> Wt[n][k] hi/lo ----------------
__global__ __launch_bounds__(256) void split_wT(const float* __restrict__ Wq,
                                                const float* __restrict__ Wk,
                                                const float* __restrict__ Wv,
                                                const float* __restrict__ Wo,
                                                short* __restrict__ WT) {
  __shared__ float T[64][68];
  const int z = blockIdx.z;
  const float* W = z == 0 ? Wq : z == 1 ? Wk : z == 2 ? Wv : Wo;
  short* oh = WT + (size_t)z * 2097152;
  short* ol = oh + 1048576;
  const int n0 = blockIdx.x * 64, k0 = blockIdx.y * 64;
  const int tid = threadIdx.x;
#pragma unroll
  for (int i = 0; i < 4; ++i) {
    int slot = tid + i * 256;
    int r = slot >> 4, c4 = (slot & 15) << 2;
    *(float4*)&T[r][c4] = *(const float4*)(W + (size_t)(k0 + r) * Cc + n0 + c4);
  }
  __syncthreads();
#pragma unroll
  for (int i = 0; i < 2; ++i) {
    int slot = tid + i * 256;
    int nl = slot >> 3, ks = (slot & 7) << 3;
    short8v h, l;
#pragma unroll
    for (int e = 0; e < 8; ++e) {
      float v = T[ks + e][nl];
      short hb = f2bf(v);
      h[e] = hb;
      l[e] = f2bf(v - bf2f(hb));
    }
    *(short8v*)(oh + (size_t)(n0 + nl) * Cc + k0 + ks) = h;
    *(short8v*)(ol + (size_t)(n0 + nl) * Cc + k0 + ks) = l;
  }
}

// ---------------- split-bf16 MFMA GEMM core ----------------
// C[128x64] tile: A[4096][1024] bf16 hi/lo row-major; B = Wt[n][k] bf16 hi/lo.
// 4 waves (2x2): wave rows wr*64+m*16, cols wc*16 + n*32 (rope pair c,c+32 in-thread).
// LDS staged via global_load_lds w=16, chunk-XOR swizzle (both sides): phys = log ^ ((row>>1)&3).
__device__ __forceinline__ void gemm_core(const short* __restrict__ Ah, const short* __restrict__ Al,
                                          const short* __restrict__ Bh, const short* __restrict__ Bl,
                                          short* AhiL, short* AloL, short* BhiL, short* BloL,
                                          int row0, int col0, int wv, int lane, f32x4 acc[4][2]) {
  const int l15 = lane & 15, g = lane >> 4;
  const int wr = wv >> 1, wc = wv & 1;

  const int slot0 = wv * 64 + lane;
  const int slot1 = slot0 + 256;
  const int ar0 = slot0 >> 2, ac0 = (((slot0 & 3) ^ ((slot0 >> 3) & 3)) << 3);
  const int ar1 = slot1 >> 2, ac1 = (((slot1 & 3) ^ ((slot1 >> 3) & 3)) << 3);
  const size_t aoff0 = (size_t)(row0 + ar0) * Cc + ac0;
  const size_t aoff1 = (size_t)(row0 + ar1) * Cc + ac1;
  const size_t boff  = (size_t)(col0 + ar0) * Cc + ac0;

  short* aHb0 = AhiL + wv * 512;
  short* aHb1 = AhiL + wv * 512 + 2048;
  short* aLb0 = AloL + wv * 512;
  short* aLb1 = AloL + wv * 512 + 2048;
  short* bHb  = BhiL + wv * 512;
  short* bLb  = BloL + wv * 512;

  const int chs = (g ^ ((l15 >> 1) & 3)) << 3;
  int aL[4], bL[2];
#pragma unroll
  for (int m = 0; m < 4; ++m) aL[m] = (wr * 64 + m * 16 + l15) * 32 + chs;
#pragma unroll
  for (int n = 0; n < 2; ++n) bL[n] = (wc * 16 + n * 32 + l15) * 32 + chs;

  for (int k0 = 0; k0 < Cc; k0 += 32) {
    __syncthreads();
    gll16(Ah + aoff0 + k0, aHb0);
    gll16(Ah + aoff1 + k0, aHb1);
    gll16(Al + aoff0 + k0, aLb0);
    gll16(Al + aoff1 + k0, aLb1);
    gll16(Bh + boff + k0, bHb);
    gll16(Bl + boff + k0, bLb);
    __syncthreads();
    short8v ah[4], al[4], bh[2], bl[2];
#pragma unroll
    for (int m = 0; m < 4; ++m) {
      ah[m] = *(short8v*)&AhiL[aL[m]];
      al[m] = *(short8v*)&AloL[aL[m]];
    }
#pragma unroll
    for (int n = 0; n < 2; ++n) {
      bh[n] = *(short8v*)&BhiL[bL[n]];
      bl[n] = *(short8v*)&BloL[bL[n]];
    }
#pragma unroll
    for (int m = 0; m < 4; ++m)
#pragma unroll
      for (int n = 0; n < 2; ++n) {
        acc[m][n] = __builtin_amdgcn_mfma_f32_16x16x32_bf16(ah[m], bh[n], acc[m][n], 0, 0, 0);
        acc[m][n] = __builtin_amdgcn_mfma_f32_16x16x32_bf16(ah[m], bl[n], acc[m][n], 0, 0, 0);
        acc[m][n] = __builtin_amdgcn_mfma_f32_16x16x32_bf16(al[m], bh[n], acc[m][n], 0, 0, 0);
      }
  }
}

// ---------------- QKV projection GEMM (+rope for Q/K, bf16 out [B,H,T,D]) ----------------
__global__ __launch_bounds__(256) void gemm_qkv(const short* __restrict__ xhi,
                                                const short* __restrict__ xlo,
                                                const short* __restrict__ WT,
                                                const float* __restrict__ bq,
                                                const float* __restrict__ bk,
                                                const float* __restrict__ bv,
                                                short* __restrict__ qb,
                                                short* __restrict__ kb,
                                                short* __restrict__ vb) {
  __shared__ short AhiL[128 * 32], AloL[128 * 32], BhiL[64 * 32], BloL[64 * 32];
  const int mode = blockIdx.y;
  const short* Bh = WT + (size_t)mode * 2097152;
  const short* Bl = Bh + 1048576;
  const float* bias = mode == 0 ? bq : mode == 1 ? bk : bv;
  short* Y = mode == 0 ? qb : mode == 1 ? kb : vb;

  const int bid = blockIdx.x;
  const int nid = ((bid & 7) << 6) | (bid >> 3);   // XCD swizzle (512 blocks)
  const int row0 = (nid >> 4) * 128, col0 = (nid & 15) * 64;
  const int lane = threadIdx.x & 63, wv = threadIdx.x >> 6;
  const int l15 = lane & 15, g = lane >> 4;
  const int wr = wv >> 1, wc = wv & 1;

  f32x4 acc[4][2];
#pragma unroll
  for (int m = 0; m < 4; ++m)
#pragma unroll
    for (int n = 0; n < 2; ++n) acc[m][n] = (f32x4){0.f, 0.f, 0.f, 0.f};

  gemm_core(xhi, xlo, Bh, Bl, AhiL, AloL, BhiL, BloL, row0, col0, wv, lane, acc);

  const int cA = col0 + wc * 16 + l15;   // low column of the (c, c+32) pair
  const int h = cA >> 6, d = cA & 63;    // d in [0,32)
  const float b0 = bias[cA], b1 = bias[cA + 32];

  if (mode < 2) {
    const float scale = (mode == 0) ? 0.125f : 1.0f;
    const float inv = exp2f(-(float)(cA & 31) * (13.2877123795494f / 32.f));
#pragma unroll
    for (int m = 0; m < 4; ++m)
#pragma unroll
      for (int rr = 0; rr < 4; ++rr) {
        int R = row0 + wr * 64 + m * 16 + g * 4 + rr;
        int bI = R >> 11, t = R & (Tt - 1);
        float sn, cs;
        sincosf((float)t * inv, &sn, &cs);
        float v0 = acc[m][0][rr] + b0, v1 = acc[m][1][rr] + b1;
        size_t base = (((size_t)(bI * Hh + h) * Tt + t) << 6) + d;
        Y[base]      = f2bf((v0 * cs - v1 * sn) * scale);
        Y[base + 32] = f2bf((v1 * cs + v0 * sn) * scale);
      }
  } else {
#pragma unroll
    for (int m = 0; m < 4; ++m)
#pragma unroll
      for (int rr = 0; rr < 4; ++rr) {
        int R = row0 + wr * 64 + m * 16 + g * 4 + rr;
        int bI = R >> 11, t = R & (Tt - 1);
        size_t base = (((size_t)(bI * Hh + h) * Tt + t) << 6) + d;
        Y[base]      = f2bf(acc[m][0][rr] + b0);
        Y[base + 32] = f2bf(acc[m][1][rr] + b1);
      }
  }
}

// ---------------- final output GEMM: d_out = attn @ Wo + bo (fp32 out) ----------------
__global__ __launch_bounds__(256) void gemm_out(const short* __restrict__ ahi,
                                                const short* __restrict__ alo,
                                                const short* __restrict__ WTo,
                                                const float* __restrict__ bias,
                                                float* __restrict__ Y) {
  __shared__ short AhiL[128 * 32], AloL[128 * 32], BhiL[64 * 32], BloL[64 * 32];
  const short* Bh = WTo;
  const short* Bl = WTo + 1048576;

  const int bid = blockIdx.x;
  const int nid = ((bid & 7) << 6) | (bid >> 3);
  const int row0 = (nid >> 4) * 128, col0 = (nid & 15) * 64;
  const int lane = threadIdx.x & 63, wv = threadIdx.x >> 6;
  const int l15 = lane & 15, g = lane >> 4;
  const int wr = wv >> 1, wc = wv & 1;

  f32x4 acc[4][2];
#pragma unroll
  for (int m = 0; m < 4; ++m)
#pragma unroll
    for (int n = 0; n < 2; ++n) acc[m][n] = (f32x4){0.f, 0.f, 0.f, 0.f};

  gemm_core(ahi, alo, Bh, Bl, AhiL, AloL, BhiL, BloL, row0, col0, wv, lane, acc);

  const int cA = col0 + wc * 16 + l15;
  const float b0 = bias[cA], b1 = bias[cA + 32];
#pragma unroll
  for (int m = 0; m < 4; ++m)
#pragma unroll
    for (int rr = 0; rr < 4; ++rr) {
      int R = row0 + wr * 64 + m * 16 + g * 4 + rr;
      Y[(size_t)R * Cc + cA]      = acc[m][0][rr] + b0;
      Y[(size_t)R * Cc + cA + 32] = acc[m][1][rr] + b1;
    }
}

// ---------------- MFMA flash attention (bf16 in, split hi/lo bf16 out) ----------------
__global__ __launch_bounds__(256) void attn_mfma(const short* __restrict__ q,
                                                 const short* __restrict__ k,
                                                 const short* __restrict__ v,
                                                 short* __restrict__ ohi,
                                                 short* __restrict__ olo) {
  const int n = blockIdx.x;
  const int xcd = n & 7;
  const int slot = n >> 3;
  const int bh = xcd * 4 + (slot >> 5);
  const int qblk = slot & 31;
  const int q0 = qblk * 64;

  const int lane = threadIdx.x & 63;
  const int wv = threadIdx.x >> 6;
  const int l15 = lane & 15;
  const int g = lane >> 4;
  const int qbase = q0 + wv * 16;
  const int qrow = qbase + l15;

  const short* qgb = q + (size_t)bh * Tt * Dd;
  const short* kgb = k + (size_t)bh * Tt * Dd;
  const short* vgb = v + (size_t)bh * Tt * Dd;

  const short8v qlo = *(const short8v*)(qgb + (size_t)qrow * Dd + 8 * g);
  const short8v qhi = *(const short8v*)(qgb + (size_t)qrow * Dd + 32 + 8 * g);

  __shared__ short Klds[32 * 72];
  __shared__ short Vt[64 * 40];

  f32x4 oacc[4];
#pragma unroll
  for (int i = 0; i < 4; ++i) oacc[i] = (f32x4){0.f, 0.f, 0.f, 0.f};
  float mrun = -1e30f, lrun = 0.f;

  const int cs0 = (q0 - 511) > 0 ? (q0 - 511) : 0;
  const int cstart = cs0 & ~31;

  for (int jt = cstart; jt < Tt; jt += 32) {
    __syncthreads();
    {  // stage K (bf16 copy)
      int kr = threadIdx.x >> 3;
      int kc = (threadIdx.x & 7) * 8;
      *(short8v*)&Klds[kr * 72 + kc] = *(const short8v*)(kgb + (size_t)(jt + kr) * Dd + kc);
    }
    {  // stage V transposed + psi-permuted
      int vr = (threadIdx.x >> 4) * 2;
      int vc = (threadIdx.x & 15) * 4;
      const short* s0 = vgb + (size_t)(jt + vr) * Dd + vc;
      short4v a = *(const short4v*)s0;
      short4v b = *(const short4v*)(s0 + Dd);
      int cc = (vr < 16) ? ((vr >> 2) * 8 + (vr & 3))
                         : (((vr - 16) >> 2) * 8 + 4 + (vr & 3));
#pragma unroll
      for (int e = 0; e < 4; ++e) {
        unsigned w = (unsigned)(unsigned short)a[e] | ((unsigned)(unsigned short)b[e] << 16);
        *(unsigned*)&Vt[(vc + e) * 40 + cc] = w;
      }
    }
    __syncthreads();

    if (jt + 32 <= qbase - 511) continue;

    short8v k00 = *(short8v*)&Klds[l15 * 72 + 8 * g];
    short8v k01 = *(short8v*)&Klds[l15 * 72 + 32 + 8 * g];
    short8v k10 = *(short8v*)&Klds[(16 + l15) * 72 + 8 * g];
    short8v k11 = *(short8v*)&Klds[(16 + l15) * 72 + 32 + 8 * g];
    f32x4 zf = (f32x4){0.f, 0.f, 0.f, 0.f};
    f32x4 s0 = __builtin_amdgcn_mfma_f32_16x16x32_bf16(k00, qlo, zf, 0, 0, 0);
    s0 = __builtin_amdgcn_mfma_f32_16x16x32_bf16(k01, qhi, s0, 0, 0, 0);
    f32x4 s1 = __builtin_amdgcn_mfma_f32_16x16x32_bf16(k10, qlo, zf, 0, 0, 0);
    s1 = __builtin_amdgcn_mfma_f32_16x16x32_bf16(k11, qhi, s1, 0, 0, 0);

    float se[8];
#pragma unroll
    for (int r = 0; r < 4; ++r) { se[r] = s0[r]; se[4 + r] = s1[r]; }

    if (jt < qbase - 496) {
      int th = qrow - 511 - jt;
#pragma unroll
      for (int r = 0; r < 4; ++r) {
        if (4 * g + r < th) se[r] = -1e30f;
        if (16 + 4 * g + r < th) se[4 + r] = -1e30f;
      }
    }

    float cmax = se[0];
#pragma unroll
    for (int i = 1; i < 8; ++i) cmax = fmaxf(cmax, se[i]);
    cmax = fmaxf(cmax, __shfl_xor(cmax, 16));
    cmax = fmaxf(cmax, __shfl_xor(cmax, 32));

    float mnew = fmaxf(fmaxf(mrun, cmax), -1e29f);
    float fac = __expf(mrun - mnew);
    float p[8], psum = 0.f;
#pragma unroll
    for (int i = 0; i < 8; ++i) { p[i] = __expf(se[i] - mnew); psum += p[i]; }
    psum += __shfl_xor(psum, 16);
    psum += __shfl_xor(psum, 32);
    lrun = lrun * fac + psum;
    mrun = mnew;
#pragma unroll
    for (int t2 = 0; t2 < 4; ++t2)
#pragma unroll
      for (int r = 0; r < 4; ++r) oacc[t2][r] *= fac;

    short8v pf;
#pragma unroll
    for (int i = 0; i < 8; ++i) pf[i] = f2bf(p[i]);

#pragma unroll
    for (int t2 = 0; t2 < 4; ++t2) {
      short8v vf = *(short8v*)&Vt[(16 * t2 + l15) * 40 + 8 * g];
      oacc[t2] = __builtin_amdgcn_mfma_f32_16x16x32_bf16(vf, pf, oacc[t2], 0, 0, 0);
    }
  }

  const float invl = 1.f / lrun;
  const int bI = bh >> 4, h = bh & 15;
  short* oh = ohi + ((size_t)(bI * Tt + qrow)) * Cc + h * Dd;
  short* ol = olo + ((size_t)(bI * Tt + qrow)) * Cc + h * Dd;
#pragma unroll
  for (int t2 = 0; t2 < 4; ++t2) {
    short4v hv, lv;
#pragma unroll
    for (int r = 0; r < 4; ++r) {
      float val = oacc[t2][r] * invl;
      short hb = f2bf(val);
      hv[r] = hb;
      lv[r] = f2bf(val - bf2f(hb));
    }
    int d0 = 16 * t2 + 4 * g;
    *(short4v*)(oh + d0) = hv;
    *(short4v*)(ol + d0) = lv;
  }
}

extern "C" void kernel_launch(void* const* d_in, const int* in_sizes, int n_in,
                              void* d_out, int out_size, void* d_ws, size_t ws_size,
                              hipStream_t stream) {
  const float* x  = (const float*)d_in[0];
  const float* Wq = (const float*)d_in[1];
  const float* bq = (const float*)d_in[2];
  const float* Wk = (const float*)d_in[3];
  const float* bk = (const float*)d_in[4];
  const float* Wv = (const float*)d_in[5];
  const float* bv = (const float*)d_in[6];
  const float* Wo = (const float*)d_in[7];
  const float* bo = (const float*)d_in[8];

  short* ws16 = (short*)d_ws;
  short* xhi = ws16;                  // 8MB; reused as attn_hi after projections
  short* xlo = ws16 + 4194304;        // 8MB; reused as attn_lo
  short* WT  = ws16 + 8388608;        // 16MB: q_hi,q_lo,k_hi,k_lo,v_hi,v_lo,o_hi,o_lo
  short* qb  = ws16 + 16777216;       // 8MB bf16 [B,H,T,D]
  short* kb  = ws16 + 20971520;       // 8MB
  short* vb  = ws16 + 25165824;       // 8MB

  split_x<<<2048, 256, 0, stream>>>(x, xhi, xlo);
  split_wT<<<dim3(16, 16, 4), 256, 0, stream>>>(Wq, Wk, Wv, Wo, WT);

  gemm_qkv<<<dim3(512, 3), 256, 0, stream>>>(xhi, xlo, WT, bq, bk, bv, qb, kb, vb);

  attn_mfma<<<1024, 256, 0, stream>>>(qb, kb, vb, xhi, xlo);

  gemm_out<<<512, 256, 0, stream>>>(xhi, xlo, WT + 6 * 1048576, bo, (float*)d_out);
}

// Round 5
// 217.565 us; speedup vs baseline: 8.3100x; 1.0718x over previous
//
#include <hip/hip_runtime.h>
#include <hip/hip_bf16.h>
#include <math.h>

#define Bsz 2
#define Tt  2048
#define Cc  1024
#define Hh  16
#define Dd  64

typedef __attribute__((ext_vector_type(8))) short short8v;
typedef __attribute__((ext_vector_type(4))) short short4v;
typedef __attribute__((ext_vector_type(4))) float f32x4;

static __device__ __forceinline__ short f2bf(float f) {
  __hip_bfloat16 h = __float2bfloat16(f);
  return __builtin_bit_cast(short, h);
}
static __device__ __forceinline__ float bf2f(short s) {
  unsigned u = ((unsigned)(unsigned short)s) << 16;
  return __builtin_bit_cast(float, u);
}
static __device__ __forceinline__ void gll16(const void* g, void* l) {
  __builtin_amdgcn_global_load_lds((const __attribute__((address_space(1))) unsigned int*)g,
                                   (__attribute__((address_space(3))) unsigned int*)l, 16, 0, 0);
}

// ---------------- prepass: split x into bf16 hi/lo ----------------
__global__ void split_x(const float* __restrict__ x, short* __restrict__ xhi,
                        short* __restrict__ xlo) {
  int t = blockIdx.x * 256 + threadIdx.x;
  const float* s = x + (size_t)t * 8;
  float4 a = *(const float4*)s, b = *(const float4*)(s + 4);
  float vv[8] = {a.x, a.y, a.z, a.w, b.x, b.y, b.z, b.w};
  short8v h, l;
#pragma unroll
  for (int e = 0; e < 8; ++e) {
    short hb = f2bf(vv[e]);
    h[e] = hb;
    l[e] = f2bf(vv[e] - bf2f(hb));
  }
  *(short8v*)(xhi + (size_t)t * 8) = h;
  *(short8v*)(xlo + (size_t)t * 8) = l;
}

// ---------------- prepass: split + transpose W -> Wt[n][k] hi/lo ----------------
__global__ __launch_bounds__(256) void split_wT(const float* __restrict__ Wq,
                                                const float* __restrict__ Wk,
                                                const float* __restrict__ Wv,
                                                const float* __restrict__ Wo,
                                                short* __restrict__ WT) {
  __shared__ float T[64][68];
  const int z = blockIdx.z;
  const float* W = z == 0 ? Wq : z == 1 ? Wk : z == 2 ? Wv : Wo;
  short* oh = WT + (size_t)z * 2097152;
  short* ol = oh + 1048576;
  const int n0 = blockIdx.x * 64, k0 = blockIdx.y * 64;
  const int tid = threadIdx.x;
#pragma unroll
  for (int i = 0; i < 4; ++i) {
    int slot = tid + i * 256;
    int r = slot >> 4, c4 = (slot & 15) << 2;
    *(float4*)&T[r][c4] = *(const float4*)(W + (size_t)(k0 + r) * Cc + n0 + c4);
  }
  __syncthreads();
#pragma unroll
  for (int i = 0; i < 2; ++i) {
    int slot = tid + i * 256;
    int nl = slot >> 3, ks = (slot & 7) << 3;
    short8v h, l;
#pragma unroll
    for (int e = 0; e < 8; ++e) {
      float v = T[ks + e][nl];
      short hb = f2bf(v);
      h[e] = hb;
      l[e] = f2bf(v - bf2f(hb));
    }
    *(short8v*)(oh + (size_t)(n0 + nl) * Cc + k0 + ks) = h;
    *(short8v*)(ol + (size_t)(n0 + nl) * Cc + k0 + ks) = l;
  }
}

// ================= NEW 128x128 split-bf16 GEMM (QKV projections) =================
// 4 waves (2x2), wave tile 64x64 (acc[4][4]); BK=32. 48 MFMA : 16 ds_read_b128.
// LDS [128][32] per operand, chunk-XOR swizzle: phys16B = log16B ^ (row&3).
// Staged via global_load_lds w=16 with pre-swizzled global source (rule #21).
__global__ __launch_bounds__(256, 3) void gemm_qkv(const short* __restrict__ xhi,
                                                   const short* __restrict__ xlo,
                                                   const short* __restrict__ WT,
                                                   const float* __restrict__ bq,
                                                   const float* __restrict__ bk,
                                                   const float* __restrict__ bv,
                                                   short* __restrict__ qb,
                                                   short* __restrict__ kb,
                                                   short* __restrict__ vb) {
  __shared__ short AhiL[4096], AloL[4096], BhiL[4096], BloL[4096];
  const int mode = blockIdx.y;
  const short* Bh = WT + (size_t)mode * 2097152;
  const short* Bl = Bh + 1048576;
  const float* bias = mode == 0 ? bq : mode == 1 ? bk : bv;
  short* Y = mode == 0 ? qb : mode == 1 ? kb : vb;

  const int bid = blockIdx.x;                      // 256 blocks
  const int nid = ((bid & 7) << 5) | (bid >> 3);   // XCD swizzle
  const int row0 = (nid >> 3) * 128, col0 = (nid & 7) * 128;
  const int lane = threadIdx.x & 63, wv = threadIdx.x >> 6;
  const int l15 = lane & 15, g = lane >> 4;
  const int wr = wv >> 1, wc = wv & 1;

  // staging: wave wv covers rows 32wv..32wv+31; 2 glls of 16 rows each
  const int srow0 = wv * 32 + (lane >> 2);
  const int srow1 = srow0 + 16;
  const int sch0 = ((lane & 3) ^ ((lane >> 2) & 3)) << 3;  // log chunk (shorts)
  const size_t aoff0 = (size_t)(row0 + srow0) * Cc + sch0;
  const size_t aoff1 = (size_t)(row0 + srow1) * Cc + sch0;
  const size_t boff0 = (size_t)(col0 + srow0) * Cc + sch0;
  const size_t boff1 = (size_t)(col0 + srow1) * Cc + sch0;
  short* dA0 = AhiL + wv * 1024;  short* dA1 = dA0 + 512;
  short* dAl0 = AloL + wv * 1024; short* dAl1 = dAl0 + 512;
  short* dB0 = BhiL + wv * 1024;  short* dB1 = dB0 + 512;
  short* dBl0 = BloL + wv * 1024; short* dBl1 = dBl0 + 512;

  // fragment read offsets (shorts): row*32 + (g ^ (l15&3))*8
  int aL[4], bL[4];
#pragma unroll
  for (int m = 0; m < 4; ++m) aL[m] = (wr * 64 + m * 16 + l15) * 32 + ((g ^ (l15 & 3)) << 3);
#pragma unroll
  for (int n = 0; n < 4; ++n) bL[n] = (wc * 64 + n * 16 + l15) * 32 + ((g ^ (l15 & 3)) << 3);

  f32x4 acc[4][4];
#pragma unroll
  for (int m = 0; m < 4; ++m)
#pragma unroll
    for (int n = 0; n < 4; ++n) acc[m][n] = (f32x4){0.f, 0.f, 0.f, 0.f};

  for (int k0 = 0; k0 < Cc; k0 += 32) {
    __syncthreads();
    gll16(xhi + aoff0 + k0, dA0);
    gll16(xhi + aoff1 + k0, dA1);
    gll16(xlo + aoff0 + k0, dAl0);
    gll16(xlo + aoff1 + k0, dAl1);
    gll16(Bh + boff0 + k0, dB0);
    gll16(Bh + boff1 + k0, dB1);
    gll16(Bl + boff0 + k0, dBl0);
    gll16(Bl + boff1 + k0, dBl1);
    __syncthreads();
    short8v ah[4], al[4], bh[4], bl[4];
#pragma unroll
    for (int m = 0; m < 4; ++m) {
      ah[m] = *(short8v*)&AhiL[aL[m]];
      al[m] = *(short8v*)&AloL[aL[m]];
    }
#pragma unroll
    for (int n = 0; n < 4; ++n) {
      bh[n] = *(short8v*)&BhiL[bL[n]];
      bl[n] = *(short8v*)&BloL[bL[n]];
    }
#pragma unroll
    for (int m = 0; m < 4; ++m)
#pragma unroll
      for (int n = 0; n < 4; ++n) {
        acc[m][n] = __builtin_amdgcn_mfma_f32_16x16x32_bf16(ah[m], bh[n], acc[m][n], 0, 0, 0);
        acc[m][n] = __builtin_amdgcn_mfma_f32_16x16x32_bf16(ah[m], bl[n], acc[m][n], 0, 0, 0);
        acc[m][n] = __builtin_amdgcn_mfma_f32_16x16x32_bf16(al[m], bh[n], acc[m][n], 0, 0, 0);
      }
  }

  // epilogue: cols c = col0 + wc*64 + n*16 + l15 (n=0,1) pair with c+32 (n+2)
  const int cbase = col0 + wc * 64;
  const int h = cbase >> 6;   // n*16+l15 < 64
  if (mode < 2) {
    const float scale = (mode == 0) ? 0.18033688f : 1.0f;   // 1/8 * log2(e) folded for Q
#pragma unroll
    for (int n = 0; n < 2; ++n) {
      const int d = n * 16 + l15;                 // in [0,32)
      const float b0 = bias[cbase + d], b1 = bias[cbase + d + 32];
      const float inv = exp2f(-(float)d * (13.2877123795494f / 32.f));
#pragma unroll
      for (int m = 0; m < 4; ++m)
#pragma unroll
        for (int rr = 0; rr < 4; ++rr) {
          int R = row0 + wr * 64 + m * 16 + g * 4 + rr;
          int bI = R >> 11, t = R & (Tt - 1);
          float sn, cs;
          sincosf((float)t * inv, &sn, &cs);
          float v0 = acc[m][n][rr] + b0, v1 = acc[m][n + 2][rr] + b1;
          size_t base = (((size_t)(bI * Hh + h) * Tt + t) << 6) + d;
          Y[base]      = f2bf((v0 * cs - v1 * sn) * scale);
          Y[base + 32] = f2bf((v1 * cs + v0 * sn) * scale);
        }
    }
  } else {
#pragma unroll
    for (int n = 0; n < 2; ++n) {
      const int d = n * 16 + l15;
      const float b0 = bias[cbase + d], b1 = bias[cbase + d + 32];
#pragma unroll
      for (int m = 0; m < 4; ++m)
#pragma unroll
        for (int rr = 0; rr < 4; ++rr) {
          int R = row0 + wr * 64 + m * 16 + g * 4 + rr;
          int bI = R >> 11, t = R & (Tt - 1);
          size_t base = (((size_t)(bI * Hh + h) * Tt + t) << 6) + d;
          Y[base]      = f2bf(acc[m][n][rr] + b0);
          Y[base + 32] = f2bf(acc[m][n + 2][rr] + b1);
        }
    }
  }
}

// ================= old 128x64 split-bf16 core (kept for gemm_out) =================
__device__ __forceinline__ void gemm_core(const short* __restrict__ Ah, const short* __restrict__ Al,
                                          const short* __restrict__ Bh, const short* __restrict__ Bl,
                                          short* AhiL, short* AloL, short* BhiL, short* BloL,
                                          int row0, int col0, int wv, int lane, f32x4 acc[4][2]) {
  const int l15 = lane & 15, g = lane >> 4;
  const int wr = wv >> 1, wc = wv & 1;

  const int slot0 = wv * 64 + lane;
  const int slot1 = slot0 + 256;
  const int ar0 = slot0 >> 2, ac0 = (((slot0 & 3) ^ ((slot0 >> 3) & 3)) << 3);
  const int ar1 = slot1 >> 2, ac1 = (((slot1 & 3) ^ ((slot1 >> 3) & 3)) << 3);
  const size_t aoff0 = (size_t)(row0 + ar0) * Cc + ac0;
  const size_t aoff1 = (size_t)(row0 + ar1) * Cc + ac1;
  const size_t boff  = (size_t)(col0 + ar0) * Cc + ac0;

  short* aHb0 = AhiL + wv * 512;
  short* aHb1 = AhiL + wv * 512 + 2048;
  short* aLb0 = AloL + wv * 512;
  short* aLb1 = AloL + wv * 512 + 2048;
  short* bHb  = BhiL + wv * 512;
  short* bLb  = BloL + wv * 512;

  const int chs = (g ^ ((l15 >> 1) & 3)) << 3;
  int aL[4], bL[2];
#pragma unroll
  for (int m = 0; m < 4; ++m) aL[m] = (wr * 64 + m * 16 + l15) * 32 + chs;
#pragma unroll
  for (int n = 0; n < 2; ++n) bL[n] = (wc * 16 + n * 32 + l15) * 32 + chs;

  for (int k0 = 0; k0 < Cc; k0 += 32) {
    __syncthreads();
    gll16(Ah + aoff0 + k0, aHb0);
    gll16(Ah + aoff1 + k0, aHb1);
    gll16(Al + aoff0 + k0, aLb0);
    gll16(Al + aoff1 + k0, aLb1);
    gll16(Bh + boff + k0, bHb);
    gll16(Bl + boff + k0, bLb);
    __syncthreads();
    short8v ah[4], al[4], bh[2], bl[2];
#pragma unroll
    for (int m = 0; m < 4; ++m) {
      ah[m] = *(short8v*)&AhiL[aL[m]];
      al[m] = *(short8v*)&AloL[aL[m]];
    }
#pragma unroll
    for (int n = 0; n < 2; ++n) {
      bh[n] = *(short8v*)&BhiL[bL[n]];
      bl[n] = *(short8v*)&BloL[bL[n]];
    }
#pragma unroll
    for (int m = 0; m < 4; ++m)
#pragma unroll
      for (int n = 0; n < 2; ++n) {
        acc[m][n] = __builtin_amdgcn_mfma_f32_16x16x32_bf16(ah[m], bh[n], acc[m][n], 0, 0, 0);
        acc[m][n] = __builtin_amdgcn_mfma_f32_16x16x32_bf16(ah[m], bl[n], acc[m][n], 0, 0, 0);
        acc[m][n] = __builtin_amdgcn_mfma_f32_16x16x32_bf16(al[m], bh[n], acc[m][n], 0, 0, 0);
      }
  }
}

__global__ __launch_bounds__(256) void gemm_out(const short* __restrict__ ahi,
                                                const short* __restrict__ alo,
                                                const short* __restrict__ WTo,
                                                const float* __restrict__ bias,
                                                float* __restrict__ Y) {
  __shared__ short AhiL[128 * 32], AloL[128 * 32], BhiL[64 * 32], BloL[64 * 32];
  const short* Bh = WTo;
  const short* Bl = WTo + 1048576;

  const int bid = blockIdx.x;
  const int nid = ((bid & 7) << 6) | (bid >> 3);
  const int row0 = (nid >> 4) * 128, col0 = (nid & 15) * 64;
  const int lane = threadIdx.x & 63, wv = threadIdx.x >> 6;
  const int l15 = lane & 15, g = lane >> 4;
  const int wr = wv >> 1, wc = wv & 1;

  f32x4 acc[4][2];
#pragma unroll
  for (int m = 0; m < 4; ++m)
#pragma unroll
    for (int n = 0; n < 2; ++n) acc[m][n] = (f32x4){0.f, 0.f, 0.f, 0.f};

  gemm_core(ahi, alo, Bh, Bl, AhiL, AloL, BhiL, BloL, row0, col0, wv, lane, acc);

  const int cA = col0 + wc * 16 + l15;
  const float b0 = bias[cA], b1 = bias[cA + 32];
#pragma unroll
  for (int m = 0; m < 4; ++m)
#pragma unroll
    for (int rr = 0; rr < 4; ++rr) {
      int R = row0 + wr * 64 + m * 16 + g * 4 + rr;
      Y[(size_t)R * Cc + cA]      = acc[m][0][rr] + b0;
      Y[(size_t)R * Cc + cA + 32] = acc[m][1][rr] + b1;
    }
}

// ================= MFMA flash attention v2 =================
// Double-buffered LDS, 1 barrier/chunk. K staged via global_load_lds with
// XOR-chunk swizzle (phys16B = log16B ^ (row&7), pre-swizzled source).
// V global loads prefetched one chunk ahead. Softmax in exp2 domain
// (log2e folded into Q), defer-max rescale skip (THR=8).
__global__ __launch_bounds__(256, 4) void attn_mfma(const short* __restrict__ q,
                                                    const short* __restrict__ k,
                                                    const short* __restrict__ v,
                                                    short* __restrict__ ohi,
                                                    short* __restrict__ olo) {
  const int n = blockIdx.x;
  const int xcd = n & 7;
  const int slot = n >> 3;
  const int bh = xcd * 4 + (slot >> 5);
  const int qblk = slot & 31;
  const int q0 = qblk * 64;

  const int tid = threadIdx.x;
  const int lane = tid & 63;
  const int wv = tid >> 6;
  const int l15 = lane & 15;
  const int g = lane >> 4;
  const int qbase = q0 + wv * 16;
  const int qrow = qbase + l15;

  const short* qgb = q + (size_t)bh * Tt * Dd;
  const short* kgb = k + (size_t)bh * Tt * Dd;
  const short* vgb = v + (size_t)bh * Tt * Dd;

  const short8v qlo = *(const short8v*)(qgb + (size_t)qrow * Dd + 8 * g);
  const short8v qhi = *(const short8v*)(qgb + (size_t)qrow * Dd + 32 + 8 * g);

  __shared__ short Klds[2][32 * 64];
  __shared__ short Vt[2][64 * 40];

  // K staging via gll: lane covers row r8=lane>>3, phys chunk lane&7,
  // source log chunk (lane&7)^r8 (read inverts with row&7).
  const int r8 = lane >> 3;
  const int kch = ((lane & 7) ^ r8) << 3;
  const size_t ksrc_off = (size_t)(wv * 8 + r8) * Dd + kch;

  // V prefetch/write mapping (as round 4)
  const int vr = (tid >> 4) * 2;
  const int vc = (tid & 15) * 4;
  const int cc = (vr < 16) ? ((vr >> 2) * 8 + (vr & 3))
                           : (((vr - 16) >> 2) * 8 + 4 + (vr & 3));

  // K fragment read offsets (shorts)
  const int kx = l15 * 64;
  const int c0 = (g ^ (l15 & 7)) << 3;
  const int c1 = ((4 + g) ^ (l15 & 7)) << 3;

  f32x4 oacc[4];
#pragma unroll
  for (int i = 0; i < 4; ++i) oacc[i] = (f32x4){0.f, 0.f, 0.f, 0.f};
  float mrun = -1e30f, lrun = 0.f;

  const int cs0 = (q0 - 511) > 0 ? (q0 - 511) : 0;
  const int cstart = cs0 & ~31;
  const int nch = (Tt - cstart) >> 5;

  short4v va, vb2;

  // ---- prologue: stage chunk 0, prefetch V regs for chunk 1 ----
  gll16(kgb + (size_t)cstart * Dd + ksrc_off, &Klds[0][wv * 512]);
  va  = *(const short4v*)(vgb + (size_t)(cstart + vr) * Dd + vc);
  vb2 = *(const short4v*)(vgb + (size_t)(cstart + vr + 1) * Dd + vc);
#pragma unroll
  for (int e = 0; e < 4; ++e) {
    unsigned w = (unsigned)(unsigned short)va[e] | ((unsigned)(unsigned short)vb2[e] << 16);
    *(unsigned*)&Vt[0][(vc + e) * 40 + cc] = w;
  }
  if (nch > 1) {
    va  = *(const short4v*)(vgb + (size_t)(cstart + 32 + vr) * Dd + vc);
    vb2 = *(const short4v*)(vgb + (size_t)(cstart + 32 + vr + 1) * Dd + vc);
  }
  __syncthreads();

  for (int ci = 0; ci < nch; ++ci) {
    const int jt = cstart + (ci << 5);
    const int cur = ci & 1;

    // ---- stage chunk ci+1 into the other buffer ----
    if (ci + 1 < nch) {
      gll16(kgb + (size_t)(jt + 32) * Dd + ksrc_off, &Klds[cur ^ 1][wv * 512]);
#pragma unroll
      for (int e = 0; e < 4; ++e) {
        unsigned w = (unsigned)(unsigned short)va[e] | ((unsigned)(unsigned short)vb2[e] << 16);
        *(unsigned*)&Vt[cur ^ 1][(vc + e) * 40 + cc] = w;
      }
      if (ci + 2 < nch) {
        va  = *(const short4v*)(vgb + (size_t)(jt + 64 + vr) * Dd + vc);
        vb2 = *(const short4v*)(vgb + (size_t)(jt + 64 + vr + 1) * Dd + vc);
      }
    }

    // ---- compute on buffer cur ----
    if (jt + 32 > qbase - 511) {
      const short* kbuf = &Klds[cur][0];
      short8v k00 = *(short8v*)&kbuf[kx + c0];
      short8v k01 = *(short8v*)&kbuf[kx + c1];
      short8v k10 = *(short8v*)&kbuf[kx + 1024 + c0];
      short8v k11 = *(short8v*)&kbuf[kx + 1024 + c1];
      f32x4 zf = (f32x4){0.f, 0.f, 0.f, 0.f};
      f32x4 s0 = __builtin_amdgcn_mfma_f32_16x16x32_bf16(k00, qlo, zf, 0, 0, 0);
      s0 = __builtin_amdgcn_mfma_f32_16x16x32_bf16(k01, qhi, s0, 0, 0, 0);
      f32x4 s1 = __builtin_amdgcn_mfma_f32_16x16x32_bf16(k10, qlo, zf, 0, 0, 0);
      s1 = __builtin_amdgcn_mfma_f32_16x16x32_bf16(k11, qhi, s1, 0, 0, 0);

      float se[8];
#pragma unroll
      for (int r = 0; r < 4; ++r) { se[r] = s0[r]; se[4 + r] = s1[r]; }

      if (jt < qbase - 496) {
        int th = qrow - 511 - jt;
#pragma unroll
        for (int r = 0; r < 4; ++r) {
          if (4 * g + r < th) se[r] = -1e30f;
          if (16 + 4 * g + r < th) se[4 + r] = -1e30f;
        }
      }

      float cmax = se[0];
#pragma unroll
      for (int i = 1; i < 8; ++i) cmax = fmaxf(cmax, se[i]);
      cmax = fmaxf(cmax, __shfl_xor(cmax, 16));
      cmax = fmaxf(cmax, __shfl_xor(cmax, 32));

      if (!__all(cmax <= mrun + 8.0f)) {
        float mnew = fmaxf(fmaxf(mrun, cmax), -1e29f);
        float fac = exp2f(mrun - mnew);
        lrun *= fac;
#pragma unroll
        for (int t2 = 0; t2 < 4; ++t2)
#pragma unroll
          for (int r = 0; r < 4; ++r) oacc[t2][r] *= fac;
        mrun = mnew;
      }

      float p[8], psum = 0.f;
#pragma unroll
      for (int i = 0; i < 8; ++i) { p[i] = exp2f(se[i] - mrun); psum += p[i]; }
      psum += __shfl_xor(psum, 16);
      psum += __shfl_xor(psum, 32);
      lrun += psum;

      short8v pf;
#pragma unroll
      for (int i = 0; i < 8; ++i) pf[i] = f2bf(p[i]);

#pragma unroll
      for (int t2 = 0; t2 < 4; ++t2) {
        short8v vf = *(short8v*)&Vt[cur][(16 * t2 + l15) * 40 + 8 * g];
        oacc[t2] = __builtin_amdgcn_mfma_f32_16x16x32_bf16(vf, pf, oacc[t2], 0, 0, 0);
      }
    }
    __syncthreads();
  }

  const float invl = 1.f / lrun;
  const int bI = bh >> 4, h = bh & 15;
  short* oh = ohi + ((size_t)(bI * Tt + qrow)) * Cc + h * Dd;
  short* ol = olo + ((size_t)(bI * Tt + qrow)) * Cc + h * Dd;
#pragma unroll
  for (int t2 = 0; t2 < 4; ++t2) {
    short4v hv, lv;
#pragma unroll
    for (int r = 0; r < 4; ++r) {
      float val = oacc[t2][r] * invl;
      short hb = f2bf(val);
      hv[r] = hb;
      lv[r] = f2bf(val - bf2f(hb));
    }
    int d0 = 16 * t2 + 4 * g;
    *(short4v*)(oh + d0) = hv;
    *(short4v*)(ol + d0) = lv;
  }
}

extern "C" void kernel_launch(void* const* d_in, const int* in_sizes, int n_in,
                              void* d_out, int out_size, void* d_ws, size_t ws_size,
                              hipStream_t stream) {
  const float* x  = (const float*)d_in[0];
  const float* Wq = (const float*)d_in[1];
  const float* bq = (const float*)d_in[2];
  const float* Wk = (const float*)d_in[3];
  const float* bk = (const float*)d_in[4];
  const float* Wv = (const float*)d_in[5];
  const float* bv = (const float*)d_in[6];
  const float* Wo = (const float*)d_in[7];
  const float* bo = (const float*)d_in[8];

  short* ws16 = (short*)d_ws;
  short* xhi = ws16;                  // 8MB; reused as attn_hi after projections
  short* xlo = ws16 + 4194304;        // 8MB; reused as attn_lo
  short* WT  = ws16 + 8388608;        // 16MB
  short* qb  = ws16 + 16777216;       // 8MB bf16 [B,H,T,D]
  short* kb  = ws16 + 20971520;
  short* vb  = ws16 + 25165824;

  split_x<<<2048, 256, 0, stream>>>(x, xhi, xlo);
  split_wT<<<dim3(16, 16, 4), 256, 0, stream>>>(Wq, Wk, Wv, Wo, WT);

  gemm_qkv<<<dim3(256, 3), 256, 0, stream>>>(xhi, xlo, WT, bq, bk, bv, qb, kb, vb);

  attn_mfma<<<1024, 256, 0, stream>>>(qb, kb, vb, xhi, xlo);

  gemm_out<<<512, 256, 0, stream>>>(xhi, xlo, WT + 6 * 1048576, bo, (float*)d_out);
}